// Round 9
// baseline (97.666 us; speedup 1.0000x reference)
//
#include <hip/hip_runtime.h>

// CapsuleConv2d: x (4,32,56,56) f32, weight (P_out=4,P_in=4,K=9,L_in=8,L_out=16) f32
// out (4,64,56,56) f32. 3x3 conv s1 p1, 3 routing iterations.
//
// Lane = dq(bits 0-1) x wl(bits 2-3) x p(bits 4-5). dq in quad bits -> d-reductions
// are DPP quad_perm adds (VALU). T=2: wave owns tiles (h0,h0+1); one weight b128
// broadcast feeds 8 sites. M[9][4][2] = 72 VGPRs.
//
// R9: 1-deep SW pipeline on the l-loop (xv/xn double buffer): iteration l+1's 12
// x-loads issue before iteration l's FMA block -> load-use latency overlapped
// without the full-unroll register blowup (R5: 370 MB scratch). Bounds logic
// hoisted: row offset/validity wave-uniform (SGPR), col offset/validity 3 VGPRs.
//
// REGISTER LESSONS (R3-R6): any occupancy attribute forced spills (84/64/128-cap,
// up to 887 MB scratch). NO attributes + unroll(disable) keeps live set ~112.

#define HW 56
#define HW2 3136
#define WSTRIDE 1168

__device__ __forceinline__ float quad_reduce(float x) {
    int y = __builtin_amdgcn_update_dpp(0, __float_as_int(x), 0xB1, 0xF, 0xF, true);
    float s = x + __int_as_float(y);
    int z = __builtin_amdgcn_update_dpp(0, __float_as_int(s), 0x4E, 0xF, 0xF, true);
    return s + __int_as_float(z);
}

__global__ void caps_routing_kernel(
    const float* __restrict__ x, const float* __restrict__ wgt,
    float* __restrict__ out)
{
    __shared__ float lds_w[4 * WSTRIDE];   // 18688 B

    const int tid = threadIdx.x;
    const int bx  = blockIdx.x;          // n*4 + o
    const int n = bx >> 2, o = bx & 3;

    // ---- stage weight slice wgt[o][p][k][l][d] (4608 floats) into LDS ----
    {
        const float4* wsrc = (const float4*)(wgt + o * 4608);
        for (int i = tid; i < 1152; i += 256) {
            const int pp  = i / 288;          // 288 float4 per p-plane
            const int rem = i - pp * 288;
            *(float4*)&lds_w[pp * WSTRIDE + rem * 4] = wsrc[i];
        }
    }
    __syncthreads();

    const int dq = tid & 3;              // quad bits -> DPP-reducible
    const int wl = (tid >> 2) & 3;
    const int p  = (tid >> 4) & 3;

    // tile-pair index: 392 pairs = 28 h-pairs x 14 w-tiles
    const int t  = blockIdx.y * 4 + (tid >> 6);
    const int hp = t / 14;
    const int w0 = (t - hp * 14) * 4;
    const int h0 = hp * 2;               // wave covers rows h0 and h0+1

    // ---- hoisted bounds: rows wave-uniform (SGPR), cols per-lane (3 VGPR) ----
    int  rowoff[4]; bool rowok[4];
    #pragma unroll
    for (int rr = 0; rr < 4; ++rr) {
        const int row = h0 + rr - 1;
        rowok[rr]  = (unsigned)row < (unsigned)HW;
        rowoff[rr] = (row < 0 ? 0 : (row > 55 ? 55 : row)) * HW;
    }
    int  coloff[3]; bool colok[3];
    #pragma unroll
    for (int c = 0; c < 3; ++c) {
        const int col = w0 + wl - 1 + c;
        colok[c]  = (unsigned)col < (unsigned)HW;
        coloff[c] = col < 0 ? 0 : (col > 55 ? 55 : col);
    }

    const float* xpl = x + (n * 32 + p * 8) * HW2;   // l=0 plane for this p
    const float* wbase = &lds_w[p * WSTRIDE + dq * 4];

    // M[k][j][ti]: priors for the lane's 4 d's at sites (h0+ti, w0+wl)
    float M[9][4][2];
    #pragma unroll
    for (int k = 0; k < 9; ++k)
        #pragma unroll
        for (int j = 0; j < 4; ++j) { M[k][j][0] = 0.f; M[k][j][1] = 0.f; }

    auto load_block = [&](float (&dst)[4][3], int l) {
        const float* xplane = xpl + l * HW2;
        #pragma unroll
        for (int rr = 0; rr < 4; ++rr)
            #pragma unroll
            for (int c = 0; c < 3; ++c) {
                const float raw = xplane[rowoff[rr] + coloff[c]];  // clamped, in-bounds
                dst[rr][c] = (rowok[rr] && colok[c]) ? raw : 0.f;
            }
    };

    auto fma_block = [&](const float (&xv)[4][3], int l) {
        #pragma unroll
        for (int rr = 0; rr < 3; ++rr)
            #pragma unroll
            for (int kc = 0; kc < 3; ++kc) {
                const int k = rr * 3 + kc;
                const float4 wa = *(const float4*)(wbase + (k * 8 + l) * 16);
                const float xs0 = xv[rr][kc];       // tile 0 (row h0)
                const float xs1 = xv[rr + 1][kc];   // tile 1 (row h0+1)
                M[k][0][0] += xs0 * wa.x; M[k][1][0] += xs0 * wa.y;
                M[k][2][0] += xs0 * wa.z; M[k][3][0] += xs0 * wa.w;
                M[k][0][1] += xs1 * wa.x; M[k][1][1] += xs1 * wa.y;
                M[k][2][1] += xs1 * wa.z; M[k][3][1] += xs1 * wa.w;
            }
    };

    // ---- software-pipelined priors loop ----
    float xv[4][3], xn[4][3];
    load_block(xv, 0);
    #pragma clang loop unroll(disable)
    for (int l = 0; l < 7; ++l) {
        load_block(xn, l + 1);     // prefetch next plane before using current
        fma_block(xv, l);
        #pragma unroll
        for (int rr = 0; rr < 4; ++rr)
            #pragma unroll
            for (int c = 0; c < 3; ++c) xv[rr][c] = xn[rr][c];
    }
    fma_block(xv, 7);

    // ---- dynamic routing (3 iters; iter 0 uniform probs = 1/9), per tile ----
    #pragma unroll
    for (int ti = 0; ti < 2; ++ti) {
        float v[4], b[9];
        {
            float s[4];
            #pragma unroll
            for (int j = 0; j < 4; ++j) {
                float a = M[0][j][ti];
                #pragma unroll
                for (int k = 1; k < 9; ++k) a += M[k][j][ti];
                s[j] = a * (1.f / 9.f);
            }
            float sq = s[0]*s[0] + s[1]*s[1] + s[2]*s[2] + s[3]*s[3];
            sq = quad_reduce(sq);
            const float scale = sq * __builtin_amdgcn_rsqf(sq) * __builtin_amdgcn_rcpf(1.f + sq);
            #pragma unroll
            for (int j = 0; j < 4; ++j) v[j] = s[j] * scale;
            #pragma unroll
            for (int k = 0; k < 9; ++k) {
                float u = M[k][0][ti]*v[0] + M[k][1][ti]*v[1]
                        + M[k][2][ti]*v[2] + M[k][3][ti]*v[3];
                b[k] = quad_reduce(u);
            }
        }

        #pragma unroll
        for (int it = 1; it < 3; ++it) {
            float mx = b[0];
            #pragma unroll
            for (int k = 1; k < 9; ++k) mx = fmaxf(mx, b[k]);
            float e[9]; float se = 0.f;
            #pragma unroll
            for (int k = 0; k < 9; ++k) { e[k] = __expf(b[k] - mx); se += e[k]; }
            const float inv = __builtin_amdgcn_rcpf(se);
            float s[4];
            #pragma unroll
            for (int j = 0; j < 4; ++j) {
                float a = 0.f;
                #pragma unroll
                for (int k = 0; k < 9; ++k) a += e[k] * M[k][j][ti];
                s[j] = a * inv;
            }
            float sq = s[0]*s[0] + s[1]*s[1] + s[2]*s[2] + s[3]*s[3];
            sq = quad_reduce(sq);
            const float scale = sq * __builtin_amdgcn_rsqf(sq) * __builtin_amdgcn_rcpf(1.f + sq);
            #pragma unroll
            for (int j = 0; j < 4; ++j) v[j] = s[j] * scale;
            if (it == 1) {
                #pragma unroll
                for (int k = 0; k < 9; ++k) {
                    float u = M[k][0][ti]*v[0] + M[k][1][ti]*v[1]
                            + M[k][2][ti]*v[2] + M[k][3][ti]*v[3];
                    b[k] += quad_reduce(u);
                }
            }
        }

        // ---- sum over p (lane bits 4,5), store row h0+ti ----
        #pragma unroll
        for (int j = 0; j < 4; ++j) {
            v[j] += __shfl_xor(v[j], 16, 64);
            v[j] += __shfl_xor(v[j], 32, 64);
        }
        if (p == 0) {
            float* op = out + ((n * 64 + o * 16 + dq * 4) * HW + (h0 + ti)) * HW + w0 + wl;
            #pragma unroll
            for (int j = 0; j < 4; ++j) op[j * HW2] = v[j];
        }
    }
}

extern "C" void kernel_launch(void* const* d_in, const int* in_sizes, int n_in,
                              void* d_out, int out_size, void* d_ws, size_t ws_size,
                              hipStream_t stream) {
    const float* x   = (const float*)d_in[0];
    const float* wgt = (const float*)d_in[1];
    float* out = (float*)d_out;

    // grid: x = n*4+o (16), y = 98 blocks of 4 wave tile-pairs
    //       392 pairs = 28 h-pairs x 14 w-tiles
    caps_routing_kernel<<<dim3(16, 98), dim3(256), 0, stream>>>(x, wgt, out);
}

// Round 10
// 83.406 us; speedup vs baseline: 1.1710x; 1.1710x over previous
//
#include <hip/hip_runtime.h>

// CapsuleConv2d: x (4,32,56,56) f32, weight (P_out=4,P_in=4,K=9,L_in=8,L_out=16) f32
// out (4,64,56,56) f32. 3x3 conv s1 p1, 3 routing iterations.
//
// Lane = dq(bits 0-1) x wl(bits 2-3) x p(bits 4-5). dq in quad bits -> d-reductions
// are DPP quad_perm adds (VALU). T=2: wave owns tiles (h0,h0+1); one weight b128
// broadcast feeds 8 sites. M[9][4][2] = 72 VGPRs.
//
// R10: wave-uniform interior/border split. 79.6% of waves (h0 in [2,52], w0 in
// [4,48]) take the interior path: 12 raw loads/l-iter at immediate offsets
// (rr*224+c*4 B) off one base pointer -- no clamps, no cndmasks. Border waves use
// clamped (always in-bounds) addresses + zero-select.
//
// REGISTER LESSONS (R3-R9): any occupancy attribute, OR structural rewrites that
// nudge the allocator below 128 VGPR (R9: lambdas+pipeline -> VGPR 64), cause
// scratch spills (up to 887 MB). Known-good config: NO attributes,
// unroll(disable) on the l-loop, straight-line code -> 128 VGPR, zero spill (R8).

#define HW 56
#define HW2 3136
#define WSTRIDE 1168

__device__ __forceinline__ float quad_reduce(float x) {
    int y = __builtin_amdgcn_update_dpp(0, __float_as_int(x), 0xB1, 0xF, 0xF, true);
    float s = x + __int_as_float(y);
    int z = __builtin_amdgcn_update_dpp(0, __float_as_int(s), 0x4E, 0xF, 0xF, true);
    return s + __int_as_float(z);
}

__global__ void caps_routing_kernel(
    const float* __restrict__ x, const float* __restrict__ wgt,
    float* __restrict__ out)
{
    __shared__ float lds_w[4 * WSTRIDE];   // 18688 B

    const int tid = threadIdx.x;
    const int bx  = blockIdx.x;          // n*4 + o
    const int n = bx >> 2, o = bx & 3;

    // ---- stage weight slice wgt[o][p][k][l][d] (4608 floats) into LDS ----
    {
        const float4* wsrc = (const float4*)(wgt + o * 4608);
        for (int i = tid; i < 1152; i += 256) {
            const int pp  = i / 288;          // 288 float4 per p-plane
            const int rem = i - pp * 288;
            *(float4*)&lds_w[pp * WSTRIDE + rem * 4] = wsrc[i];
        }
    }
    __syncthreads();

    const int dq = tid & 3;              // quad bits -> DPP-reducible
    const int wl = (tid >> 2) & 3;
    const int p  = (tid >> 4) & 3;

    // tile-pair index: 392 pairs = 28 h-pairs x 14 w-tiles
    const int t  = blockIdx.y * 4 + (tid >> 6);
    const int hp = t / 14;
    const int w0 = (t - hp * 14) * 4;
    const int h0 = hp * 2;               // wave covers rows h0 and h0+1

    const float* xpl = x + (n * 32 + p * 8) * HW2;
    const float* wbase = &lds_w[p * WSTRIDE + dq * 4];

    // M[k][j][ti]: priors for the lane's 4 d's at sites (h0+ti, w0+wl)
    float M[9][4][2];
    #pragma unroll
    for (int k = 0; k < 9; ++k)
        #pragma unroll
        for (int j = 0; j < 4; ++j) { M[k][j][0] = 0.f; M[k][j][1] = 0.f; }

    const bool interior = (h0 >= 2) && (h0 <= 52) && (w0 >= 4) && (w0 <= 48);

    if (interior) {
        // ---- interior: raw loads, immediate offsets off one base pointer ----
        const float* xbase = xpl + (h0 - 1) * HW + (w0 + wl - 1);
        #pragma clang loop unroll(disable)
        for (int l = 0; l < 8; ++l) {
            const float* bp = xbase + l * HW2;
            float xv[4][3];
            #pragma unroll
            for (int rr = 0; rr < 4; ++rr)
                #pragma unroll
                for (int c = 0; c < 3; ++c)
                    xv[rr][c] = bp[rr * HW + c];
            #pragma unroll
            for (int rr = 0; rr < 3; ++rr)
                #pragma unroll
                for (int kc = 0; kc < 3; ++kc) {
                    const int k = rr * 3 + kc;
                    const float4 wa = *(const float4*)(wbase + (k * 8 + l) * 16);
                    const float xs0 = xv[rr][kc];
                    const float xs1 = xv[rr + 1][kc];
                    M[k][0][0] += xs0 * wa.x; M[k][1][0] += xs0 * wa.y;
                    M[k][2][0] += xs0 * wa.z; M[k][3][0] += xs0 * wa.w;
                    M[k][0][1] += xs1 * wa.x; M[k][1][1] += xs1 * wa.y;
                    M[k][2][1] += xs1 * wa.z; M[k][3][1] += xs1 * wa.w;
                }
        }
    } else {
        // ---- border: clamped (always in-bounds) addresses + zero-select ----
        int rowoff[4]; bool rowok[4];
        #pragma unroll
        for (int rr = 0; rr < 4; ++rr) {
            const int row = h0 + rr - 1;
            rowok[rr]  = (unsigned)row < (unsigned)HW;
            rowoff[rr] = (row < 0 ? 0 : (row > 55 ? 55 : row)) * HW;
        }
        int coloff[3]; bool colok[3];
        #pragma unroll
        for (int c = 0; c < 3; ++c) {
            const int col = w0 + wl - 1 + c;
            colok[c]  = (unsigned)col < (unsigned)HW;
            coloff[c] = col < 0 ? 0 : (col > 55 ? 55 : col);
        }
        #pragma clang loop unroll(disable)
        for (int l = 0; l < 8; ++l) {
            const float* xplane = xpl + l * HW2;
            float xv[4][3];
            #pragma unroll
            for (int rr = 0; rr < 4; ++rr)
                #pragma unroll
                for (int c = 0; c < 3; ++c) {
                    const float raw = xplane[rowoff[rr] + coloff[c]];
                    xv[rr][c] = (rowok[rr] && colok[c]) ? raw : 0.f;
                }
            #pragma unroll
            for (int rr = 0; rr < 3; ++rr)
                #pragma unroll
                for (int kc = 0; kc < 3; ++kc) {
                    const int k = rr * 3 + kc;
                    const float4 wa = *(const float4*)(wbase + (k * 8 + l) * 16);
                    const float xs0 = xv[rr][kc];
                    const float xs1 = xv[rr + 1][kc];
                    M[k][0][0] += xs0 * wa.x; M[k][1][0] += xs0 * wa.y;
                    M[k][2][0] += xs0 * wa.z; M[k][3][0] += xs0 * wa.w;
                    M[k][0][1] += xs1 * wa.x; M[k][1][1] += xs1 * wa.y;
                    M[k][2][1] += xs1 * wa.z; M[k][3][1] += xs1 * wa.w;
                }
        }
    }

    // ---- dynamic routing (3 iters; iter 0 uniform probs = 1/9), per tile ----
    #pragma unroll
    for (int ti = 0; ti < 2; ++ti) {
        float v[4], b[9];
        {
            float s[4];
            #pragma unroll
            for (int j = 0; j < 4; ++j) {
                float a = M[0][j][ti];
                #pragma unroll
                for (int k = 1; k < 9; ++k) a += M[k][j][ti];
                s[j] = a * (1.f / 9.f);
            }
            float sq = s[0]*s[0] + s[1]*s[1] + s[2]*s[2] + s[3]*s[3];
            sq = quad_reduce(sq);
            const float scale = sq * __builtin_amdgcn_rsqf(sq) * __builtin_amdgcn_rcpf(1.f + sq);
            #pragma unroll
            for (int j = 0; j < 4; ++j) v[j] = s[j] * scale;
            #pragma unroll
            for (int k = 0; k < 9; ++k) {
                float u = M[k][0][ti]*v[0] + M[k][1][ti]*v[1]
                        + M[k][2][ti]*v[2] + M[k][3][ti]*v[3];
                b[k] = quad_reduce(u);
            }
        }

        #pragma unroll
        for (int it = 1; it < 3; ++it) {
            float mx = b[0];
            #pragma unroll
            for (int k = 1; k < 9; ++k) mx = fmaxf(mx, b[k]);
            float e[9]; float se = 0.f;
            #pragma unroll
            for (int k = 0; k < 9; ++k) { e[k] = __expf(b[k] - mx); se += e[k]; }
            const float inv = __builtin_amdgcn_rcpf(se);
            float s[4];
            #pragma unroll
            for (int j = 0; j < 4; ++j) {
                float a = 0.f;
                #pragma unroll
                for (int k = 0; k < 9; ++k) a += e[k] * M[k][j][ti];
                s[j] = a * inv;
            }
            float sq = s[0]*s[0] + s[1]*s[1] + s[2]*s[2] + s[3]*s[3];
            sq = quad_reduce(sq);
            const float scale = sq * __builtin_amdgcn_rsqf(sq) * __builtin_amdgcn_rcpf(1.f + sq);
            #pragma unroll
            for (int j = 0; j < 4; ++j) v[j] = s[j] * scale;
            if (it == 1) {
                #pragma unroll
                for (int k = 0; k < 9; ++k) {
                    float u = M[k][0][ti]*v[0] + M[k][1][ti]*v[1]
                            + M[k][2][ti]*v[2] + M[k][3][ti]*v[3];
                    b[k] += quad_reduce(u);
                }
            }
        }

        // ---- sum over p (lane bits 4,5), store row h0+ti ----
        #pragma unroll
        for (int j = 0; j < 4; ++j) {
            v[j] += __shfl_xor(v[j], 16, 64);
            v[j] += __shfl_xor(v[j], 32, 64);
        }
        if (p == 0) {
            float* op = out + ((n * 64 + o * 16 + dq * 4) * HW + (h0 + ti)) * HW + w0 + wl;
            #pragma unroll
            for (int j = 0; j < 4; ++j) op[j * HW2] = v[j];
        }
    }
}

extern "C" void kernel_launch(void* const* d_in, const int* in_sizes, int n_in,
                              void* d_out, int out_size, void* d_ws, size_t ws_size,
                              hipStream_t stream) {
    const float* x   = (const float*)d_in[0];
    const float* wgt = (const float*)d_in[1];
    float* out = (float*)d_out;

    // grid: x = n*4+o (16), y = 98 blocks of 4 wave tile-pairs
    //       392 pairs = 28 h-pairs x 14 w-tiles
    caps_routing_kernel<<<dim3(16, 98), dim3(256), 0, stream>>>(x, wgt, out);
}

// Round 11
// 78.790 us; speedup vs baseline: 1.2396x; 1.0586x over previous
//
#include <hip/hip_runtime.h>

// CapsuleConv2d: x (4,32,56,56) f32, weight (P_out=4,P_in=4,K=9,L_in=8,L_out=16) f32
// out (4,64,56,56) f32. 3x3 conv s1 p1, 3 routing iterations.
//
// FINAL = R8 config (best measured: 77.7 us bench; kernel ~25-28 us, below the
// harness's 40 us fill dispatches).
//
// Lane = dq(bits 0-1: d-quarter) x wl(bits 2-3: 4 w-sites) x p(bits 4-5: plane).
// dq in the quad bits so d-reductions (squash norm, logit updates) are DPP
// quad_perm adds (pure VALU). T=2: each wave owns two h-adjacent tiles; one
// ds_read_b128 weight broadcast feeds 8 sites. M[9][4][2] = 72 VGPRs.
//
// REGISTER LESSONS (R3-R10, the governing constraint of this kernel):
//  - __launch_bounds__(256,N) acts as a hard min-occupancy -> forces VGPR to
//    512/(2N) and spills M to scratch (R3: 84 VGPR/887 MB, R4: 64/783 MB).
//  - amdgpu_waves_per_eu(2) still capped at 128 and full l-loop unroll clustered
//    144 loads -> live set >128 -> spill (R5: 370 MB).
//  - Lambda/pipeline restructure (R9) flipped the heuristic to 64 VGPR -> spill.
//  - Interior/border split (R10) regressed ~6 us (divergent dual path, no gain).
//  Known-good: NO occupancy attributes + unroll(disable) on the l-loop +
//  straight-line body -> 128 VGPR, zero scratch traffic.

#define HW 56
#define HW2 3136
#define WSTRIDE 1168

__device__ __forceinline__ float quad_reduce(float x) {
    int y = __builtin_amdgcn_update_dpp(0, __float_as_int(x), 0xB1, 0xF, 0xF, true);
    float s = x + __int_as_float(y);
    int z = __builtin_amdgcn_update_dpp(0, __float_as_int(s), 0x4E, 0xF, 0xF, true);
    return s + __int_as_float(z);
}

__global__ void caps_routing_kernel(
    const float* __restrict__ x, const float* __restrict__ wgt,
    float* __restrict__ out)
{
    __shared__ float lds_w[4 * WSTRIDE];   // 18688 B

    const int tid = threadIdx.x;
    const int bx  = blockIdx.x;          // n*4 + o
    const int n = bx >> 2, o = bx & 3;

    // ---- stage weight slice wgt[o][p][k][l][d] (4608 floats) into LDS ----
    {
        const float4* wsrc = (const float4*)(wgt + o * 4608);
        for (int i = tid; i < 1152; i += 256) {
            const int pp  = i / 288;          // 288 float4 per p-plane
            const int rem = i - pp * 288;
            *(float4*)&lds_w[pp * WSTRIDE + rem * 4] = wsrc[i];
        }
    }
    __syncthreads();

    const int dq = tid & 3;              // quad bits -> DPP-reducible
    const int wl = (tid >> 2) & 3;
    const int p  = (tid >> 4) & 3;

    // tile-pair index: 392 pairs = 28 h-pairs x 14 w-tiles
    const int t  = blockIdx.y * 4 + (tid >> 6);
    const int hp = t / 14;
    const int w0 = (t - hp * 14) * 4;
    const int h0 = hp * 2;               // wave covers rows h0 and h0+1

    // M[k][j][ti]: priors for the lane's 4 d's at sites (h0+ti, w0+wl)
    float M[9][4][2];
    #pragma unroll
    for (int k = 0; k < 9; ++k)
        #pragma unroll
        for (int j = 0; j < 4; ++j) { M[k][j][0] = 0.f; M[k][j][1] = 0.f; }

    const float* xp = x + (n * 32 + p * 8) * HW2;
    const float* wbase = &lds_w[p * WSTRIDE + dq * 4];
    const int colbase = w0 + wl - 1;

    #pragma clang loop unroll(disable)
    for (int l = 0; l < 8; ++l) {
        // 4 rows (h0-1 .. h0+2) x 3 cols, shared between the two tiles
        float xv[4][3];
        const float* xplane = xp + l * HW2;
        #pragma unroll
        for (int rr = 0; rr < 4; ++rr) {
            const int row = h0 + rr - 1;
            const bool rv = (unsigned)row < (unsigned)HW;
            const float* xrow = xplane + row * HW;
            #pragma unroll
            for (int c = 0; c < 3; ++c) {
                const int col = colbase + c;
                xv[rr][c] = (rv && (unsigned)col < (unsigned)HW) ? xrow[col] : 0.f;
            }
        }
        #pragma unroll
        for (int rr = 0; rr < 3; ++rr) {
            #pragma unroll
            for (int kc = 0; kc < 3; ++kc) {
                const int k = rr * 3 + kc;
                const float4 wa = *(const float4*)(wbase + (k * 8 + l) * 16);
                const float xs0 = xv[rr][kc];       // tile 0 (row h0)
                const float xs1 = xv[rr + 1][kc];   // tile 1 (row h0+1)
                M[k][0][0] += xs0 * wa.x; M[k][1][0] += xs0 * wa.y;
                M[k][2][0] += xs0 * wa.z; M[k][3][0] += xs0 * wa.w;
                M[k][0][1] += xs1 * wa.x; M[k][1][1] += xs1 * wa.y;
                M[k][2][1] += xs1 * wa.z; M[k][3][1] += xs1 * wa.w;
            }
        }
    }

    // ---- dynamic routing (3 iters; iter 0 uniform probs = 1/9), per tile ----
    #pragma unroll
    for (int ti = 0; ti < 2; ++ti) {
        float v[4], b[9];
        {
            float s[4];
            #pragma unroll
            for (int j = 0; j < 4; ++j) {
                float a = M[0][j][ti];
                #pragma unroll
                for (int k = 1; k < 9; ++k) a += M[k][j][ti];
                s[j] = a * (1.f / 9.f);
            }
            float sq = s[0]*s[0] + s[1]*s[1] + s[2]*s[2] + s[3]*s[3];
            sq = quad_reduce(sq);
            const float scale = sq * __builtin_amdgcn_rsqf(sq) * __builtin_amdgcn_rcpf(1.f + sq);
            #pragma unroll
            for (int j = 0; j < 4; ++j) v[j] = s[j] * scale;
            #pragma unroll
            for (int k = 0; k < 9; ++k) {
                float u = M[k][0][ti]*v[0] + M[k][1][ti]*v[1]
                        + M[k][2][ti]*v[2] + M[k][3][ti]*v[3];
                b[k] = quad_reduce(u);
            }
        }

        #pragma unroll
        for (int it = 1; it < 3; ++it) {
            float mx = b[0];
            #pragma unroll
            for (int k = 1; k < 9; ++k) mx = fmaxf(mx, b[k]);
            float e[9]; float se = 0.f;
            #pragma unroll
            for (int k = 0; k < 9; ++k) { e[k] = __expf(b[k] - mx); se += e[k]; }
            const float inv = __builtin_amdgcn_rcpf(se);
            float s[4];
            #pragma unroll
            for (int j = 0; j < 4; ++j) {
                float a = 0.f;
                #pragma unroll
                for (int k = 0; k < 9; ++k) a += e[k] * M[k][j][ti];
                s[j] = a * inv;
            }
            float sq = s[0]*s[0] + s[1]*s[1] + s[2]*s[2] + s[3]*s[3];
            sq = quad_reduce(sq);
            const float scale = sq * __builtin_amdgcn_rsqf(sq) * __builtin_amdgcn_rcpf(1.f + sq);
            #pragma unroll
            for (int j = 0; j < 4; ++j) v[j] = s[j] * scale;
            if (it == 1) {
                #pragma unroll
                for (int k = 0; k < 9; ++k) {
                    float u = M[k][0][ti]*v[0] + M[k][1][ti]*v[1]
                            + M[k][2][ti]*v[2] + M[k][3][ti]*v[3];
                    b[k] += quad_reduce(u);
                }
            }
        }

        // ---- sum over p (lane bits 4,5), store row h0+ti ----
        #pragma unroll
        for (int j = 0; j < 4; ++j) {
            v[j] += __shfl_xor(v[j], 16, 64);
            v[j] += __shfl_xor(v[j], 32, 64);
        }
        if (p == 0) {
            float* op = out + ((n * 64 + o * 16 + dq * 4) * HW + (h0 + ti)) * HW + w0 + wl;
            #pragma unroll
            for (int j = 0; j < 4; ++j) op[j * HW2] = v[j];
        }
    }
}

extern "C" void kernel_launch(void* const* d_in, const int* in_sizes, int n_in,
                              void* d_out, int out_size, void* d_ws, size_t ws_size,
                              hipStream_t stream) {
    const float* x   = (const float*)d_in[0];
    const float* wgt = (const float*)d_in[1];
    float* out = (float*)d_out;

    // grid: x = n*4+o (16), y = 98 blocks of 4 wave tile-pairs
    //       392 pairs = 28 h-pairs x 14 w-tiles
    caps_routing_kernel<<<dim3(16, 98), dim3(256), 0, stream>>>(x, wgt, out);
}